// Round 4
// baseline (758.750 us; speedup 1.0000x reference)
//
#include <hip/hip_runtime.h>
#include <hip/hip_bf16.h>

// Problem constants (static in the reference)
#define NN 1024
#define MM 64
#define BB 8
#define EE 63456   // sum_i min(i,64) = 2016 + 960*64

// ws float layout (fp32 scratch for collapsed weights)
#define WS_WN    0        // Wn_eff  192*64
#define WS_WE    12288    // We_eff  128*64
#define WS_BN    20480    // bn_eff  64
#define WS_BE    20544    // be_eff  64
#define WS_TOTAL 20608    // floats (~82 KB)

// Kernel A: collapse the inner linear pairs (no inner ReLU in the reference!)
//   Wn_eff = Wn1 @ Wn2, bn_eff = bn1 @ Wn2 + bn2  (same for We*). Exact algebra.
__global__ void eff_weights_kernel(
    const float* __restrict__ Wn1, const float* __restrict__ bn1,
    const float* __restrict__ Wn2, const float* __restrict__ bn2,
    const float* __restrict__ We1, const float* __restrict__ be1,
    const float* __restrict__ We2, const float* __restrict__ be2,
    float* __restrict__ ws)
{
    int idx = blockIdx.x * 256 + threadIdx.x;
    if (idx < 12288) {                       // Wn_eff (192x64)
        int r = idx >> 6, j = idx & 63;
        float acc = 0.f;
        for (int t = 0; t < 128; ++t) acc += Wn1[r * 128 + t] * Wn2[t * 64 + j];
        ws[WS_WN + idx] = acc;
    } else if (idx < 20480) {                // We_eff (128x64)
        int k = idx - 12288; int r = k >> 6, j = k & 63;
        float acc = 0.f;
        for (int t = 0; t < 128; ++t) acc += We1[r * 128 + t] * We2[t * 64 + j];
        ws[idx] = acc;
    } else if (idx < 20544) {                // bn_eff
        int j = idx - 20480;
        float acc = bn2[j];
        for (int t = 0; t < 128; ++t) acc += bn1[t] * Wn2[t * 64 + j];
        ws[idx] = acc;
    } else if (idx < WS_TOTAL) {             // be_eff
        int j = idx - 20544;
        float acc = be2[j];
        for (int t = 0; t < 128; ++t) acc += be1[t] * We2[t * 64 + j];
        ws[idx] = acc;
    }
}

// Kernel B: one block per (batch b, node i).
//  - stage the w src nodes (+dst node) and w edges into LDS (contiguous global)
//  - pair_n / pair_e via collapsed weights; pair_n summed -> agg_n -> out_nodes
//  - per-feature exclusive prefix-mean of pair_e -> out_edges
__global__ __launch_bounds__(256, 3)
void main_kernel(const float* __restrict__ nodes,
                 const float* __restrict__ edges,
                 const float* __restrict__ ws,
                 const float* __restrict__ Wnf,   // W_nodes (128x64)
                 const float* __restrict__ Wef,   // W_edges (128x64)
                 const float* __restrict__ bias,  // bias_edges (64) — used for BOTH outputs (ref does this)
                 float* __restrict__ out)
{
    __shared__ float s_nodes[65 * 64];   // rows 0..w = nodes i-w .. i
    __shared__ float s_edges[64 * 64];   // rows 0..w-1
    __shared__ float s_pair[64 * 64];    // pair_e, then overwritten with mean_e
    __shared__ float s_red[4 * 64];      // pair_n partial sums per wave-group

    const int tid = threadIdx.x;
    const int bx  = blockIdx.x;
    const int b   = bx >> 10;
    const int i   = bx & 1023;
    const int w   = (i < MM) ? i : MM;
    const long ns = (i <= 64) ? ((long)i * (i - 1)) / 2 : 2016L + (long)(i - 64) * 64;

    const float* Wn  = ws + WS_WN;
    const float* We  = ws + WS_WE;
    const float* bnE = ws + WS_BN;
    const float* beE = ws + WS_BE;

    // ---- Phase 1: stage inputs (fp32, contiguous, float4) ----
    {
        const float4* gn = (const float4*)(nodes + ((size_t)b * NN + (i - w)) * 64);
        const int nv = (w + 1) * 16;          // 16 float4 per 64-feature row
        for (int idx = tid; idx < nv; idx += 256)
            ((float4*)s_nodes)[idx] = gn[idx];
        const float4* ge = (const float4*)(edges + ((size_t)b * EE + ns) * 64);
        const int ev = w * 16;
        for (int idx = tid; idx < ev; idx += 256)
            ((float4*)s_edges)[idx] = ge[idx];
    }
    __syncthreads();

    const int f = tid & 63;      // output feature
    const int g = tid >> 6;      // wave group: handles edges j = 4m + g

    // ---- Phase 2: pair_n + pair_e, 16 edges per thread in registers ----
    float accn[16], acce[16];
    {
        // dst-node contribution is identical for every edge of this node: hoist.
        float dstdot = 0.f;
        const float* nrow = &s_nodes[w * 64];
        for (int c = 0; c < 64; ++c) dstdot += nrow[c] * Wn[(64 + c) * 64 + f];
        const float basen = dstdot + bnE[f];
        const float basee = beE[f];
#pragma unroll
        for (int m = 0; m < 16; ++m) { accn[m] = basen; acce[m] = basee; }
    }
    for (int c = 0; c < 64; c += 4) {
        float wn1[4], wn3[4], we1[4], we2[4];
#pragma unroll
        for (int q = 0; q < 4; ++q) {
            wn1[q] = Wn[(c + q) * 64 + f];          // src rows of Wn_eff
            wn3[q] = Wn[(128 + c + q) * 64 + f];    // edge rows of Wn_eff
            we1[q] = We[(c + q) * 64 + f];          // src rows of We_eff
            we2[q] = We[(64 + c + q) * 64 + f];     // edge rows of We_eff
        }
#pragma unroll
        for (int m = 0; m < 16; ++m) {
            const int j = (m << 2) + g;             // dead lanes (j>=w) compute garbage, never stored
            float4 xs = *(const float4*)&s_nodes[j * 64 + c];
            float4 xe = *(const float4*)&s_edges[j * 64 + c];
            accn[m] += xs.x * wn1[0] + xs.y * wn1[1] + xs.z * wn1[2] + xs.w * wn1[3]
                     + xe.x * wn3[0] + xe.y * wn3[1] + xe.z * wn3[2] + xe.w * wn3[3];
            acce[m] += xs.x * we1[0] + xs.y * we1[1] + xs.z * we1[2] + xs.w * we1[3]
                     + xe.x * we2[0] + xe.y * we2[1] + xe.z * we2[2] + xe.w * we2[3];
        }
    }
    {
        float sn = 0.f;
#pragma unroll
        for (int m = 0; m < 16; ++m) {
            const int j = (m << 2) + g;
            if (j < w) {
                sn += fmaxf(accn[m], 0.f);                 // pair_n, aggregated on the fly
                s_pair[j * 64 + f] = fmaxf(acce[m], 0.f);  // pair_e, kept for prefix scan
            }
        }
        s_red[g * 64 + f] = sn;
    }
    __syncthreads();

    // ---- Phase 3/4 (parallel across waves): out_nodes (wave 0), prefix scan (wave 1) ----
    if (g == 0) {
        const float invw = 1.0f / (float)((w > 0) ? w : 1);
        float acc = bias[f];
        const float* nrow = &s_nodes[w * 64];
        for (int c = 0; c < 64; ++c) {
            float aggc = (s_red[c] + s_red[64 + c] + s_red[128 + c] + s_red[192 + c]) * invw;
            acc += aggc * Wnf[c * 64 + f] + nrow[c] * Wnf[(64 + c) * 64 + f];
        }
        out[((size_t)b * NN + i) * 64 + f] = fmaxf(acc, 0.f);
    } else if (g == 1) {
        // exclusive prefix mean of pair_e along the window, in place
        float run = 0.f;
        for (int j = 0; j < w; ++j) {
            float pe = s_pair[j * 64 + f];
            s_pair[j * 64 + f] = run / (float)((j > 0) ? j : 1);
            run += pe;
        }
    }
    __syncthreads();

    // ---- Phase 5: out_edges = relu([mean_e | edge] @ W_edges + bias) ----
    float acco[16];
#pragma unroll
    for (int m = 0; m < 16; ++m) acco[m] = bias[f];
    for (int c = 0; c < 64; c += 4) {
        float w1[4], w2[4];
#pragma unroll
        for (int q = 0; q < 4; ++q) {
            w1[q] = Wef[(c + q) * 64 + f];
            w2[q] = Wef[(64 + c + q) * 64 + f];
        }
#pragma unroll
        for (int m = 0; m < 16; ++m) {
            const int j = (m << 2) + g;
            float4 xm = *(const float4*)&s_pair[j * 64 + c];
            float4 xe = *(const float4*)&s_edges[j * 64 + c];
            acco[m] += xm.x * w1[0] + xm.y * w1[1] + xm.z * w1[2] + xm.w * w1[3]
                     + xe.x * w2[0] + xe.y * w2[1] + xe.z * w2[2] + xe.w * w2[3];
        }
    }
    {
        float* oute = out + (size_t)BB * NN * 64;  // out_nodes first, then out_edges (return order)
#pragma unroll
        for (int m = 0; m < 16; ++m) {
            const int j = (m << 2) + g;
            if (j < w)
                oute[((size_t)b * EE + ns + j) * 64 + f] = fmaxf(acco[m], 0.f);
        }
    }
}

extern "C" void kernel_launch(void* const* d_in, const int* in_sizes, int n_in,
                              void* d_out, int out_size, void* d_ws, size_t ws_size,
                              hipStream_t stream) {
    const float* nodes = (const float*)d_in[0];
    const float* edges = (const float*)d_in[1];
    const float* Wn1  = (const float*)d_in[2];
    const float* bn1  = (const float*)d_in[3];
    const float* Wn2  = (const float*)d_in[4];
    const float* bn2  = (const float*)d_in[5];
    const float* We1  = (const float*)d_in[6];
    const float* be1  = (const float*)d_in[7];
    const float* We2  = (const float*)d_in[8];
    const float* be2  = (const float*)d_in[9];
    const float* Wnod = (const float*)d_in[10];
    const float* Wedg = (const float*)d_in[11];
    const float* bias = (const float*)d_in[12];
    float* ws = (float*)d_ws;
    float* out = (float*)d_out;

    hipLaunchKernelGGL(eff_weights_kernel, dim3((WS_TOTAL + 255) / 256), dim3(256), 0, stream,
                       Wn1, bn1, Wn2, bn2, We1, be1, We2, be2, ws);
    hipLaunchKernelGGL(main_kernel, dim3(BB * NN), dim3(256), 0, stream,
                       nodes, edges, ws, Wnod, Wedg, bias, out);
}